// Round 16
// baseline (484.121 us; speedup 1.0000x reference)
//
#include <hip/hip_runtime.h>
#include <math.h>

// Full-fidelity emulation of the reference as run by jax-rocm EAGERLY on this
// GPU (x64 on): every op is its own device kernel, all f64 transcendentals
// are __ocml_*_f64 == this kernel's exp()/log(). Crucially BOTH stages are
// inexact because jax lowers exp2(z) -> exp(RN(z*RN(ln2))):
//   DECODE: e = sum(bits * exp2emu(7..0)) accumulates ~1e-13 error; x is then
//           exp2emu(e-127)*(1+frac): x deviates ~1e-13 rel from the true f32
//           -> flips y32 for a handful of values (what r12/r13/r15 missed).
//   ENCODE: log2 = log(a)/RN(ln2); exp2(-e) inexact -> mant = W +- eps ->
//           floor ladder emits W-1 garbage / ladder bit flips (diag#2's 129).
// Sigmoid: exp-form 1/(1+exp(-t)) (ocml) this round.
__global__ __launch_bounds__(256) void spike_gelu_kernel(
    const uint4* __restrict__ in, uint4* __restrict__ out, int n_vals) {
#pragma clang fp contract(off)
  const double LN2 = 0x1.62e42fefa39efp-1;  // RN(ln2), XLA's folded log(2)

  // Tables (exact ocml-call replicas of the reference's constant arrays):
  //  Wdec[j] = exp2emu(7-j), j=0..7      (decode exponent weights)
  //  Vdec[j] = exp2emu(-(1+j)), j=0..22  (decode fraction weights)
  //  Lm[s]   = exp2emu(-s), s=0..22      (encode ladder scales; ebits use s<=7)
  __shared__ double Wdec[8], Vdec[23], Lm[23];
  int tid = threadIdx.x;
  if (tid < 8)       Wdec[tid]      = exp((double)(7 - tid) * LN2);
  else if (tid < 31) Vdec[tid - 8]  = exp((double)(7 - tid) * LN2);  // k=-1..-23
  else if (tid < 54) Lm[tid - 31]   = exp((double)(31 - tid) * LN2); // k=0..-22
  __syncthreads();

  int v = blockIdx.x * blockDim.x + tid;
  if (v >= n_vals) return;

  // ---- load the 32 pulses -> bit word (MSB-first)
  const uint4* p = in + (size_t)v * 8;
  uint32_t w = 0;
#pragma unroll
  for (int j = 0; j < 8; ++j) {
    uint4 b = p[j];
    w = (w << 4) | (((b.x >> 23) & 1u) << 3) | (((b.y >> 23) & 1u) << 2) |
        (((b.z >> 23) & 1u) << 1) | ((b.w >> 23) & 1u);
  }

  // ---- DECODE exactly as the reference computes it (inexact exp2 weights)
  double sign = (w >> 31) ? -1.0 : 1.0;
  double e_c = 0.0;
#pragma unroll
  for (int j = 0; j < 8; ++j)          // einsum, ascending j (listed order)
    if ((w >> (30 - j)) & 1u) e_c = e_c + Wdec[j];
  double frac_d = 0.0;
#pragma unroll
  for (int j = 0; j < 23; ++j)
    if ((w >> (22 - j)) & 1u) frac_d = frac_d + Vdec[j];

  double x;
  if (e_c > 0.0) {
    double E1 = exp((e_c - 127.0) * LN2);     // exp2emu at non-integer arg
    x = (sign * E1) * (1.0 + frac_d);
  } else {
    x = (sign * exp(-126.0 * LN2)) * frac_d;  // subnormal branch (unused)
  }

  // ---- f64 GELU, exp-form logistic, ocml exp
  double t = 1.702 * x;
  double s = 1.0 / (1.0 + exp(-t));
  double y = x * s;
  float yf = (float)y;        // astype(float32): RN
  double yd = (double)yf;     // astype(float64): exact

  // ---- ENCODE exactly as the reference computes it (inexact exp2/log2)
  double a = fabs(yd);
  uint32_t ob = 0;
  if (a > 0.0) {
    if (yd < 0.0) ob |= 0x80000000u;
    double e0 = floor(log(a) / LN2);          // jnp.log2 lowering, ocml log
    e0 = fmin(fmax(e0, -126.0), 127.0);       // jnp.clip
    double eb = e0 + 127.0;
    double p2 = exp(-e0 * LN2);               // exp2emu(-e), ocml exp
    double m1 = a * p2;                       // RN: may be W' +- eps
    double frac_e = m1 - 1.0;                 // Sterbenz-exact
    double mant = frac_e * 8388608.0;         // exact pow2 scale
    // ebits: floor(eb * exp2emu(-s)) mod 2 -> word bits 30..23
#pragma unroll
    for (int sc = 7; sc >= 0; --sc) {
      double f = floor(eb * Lm[sc]);
      double md = f - 2.0 * floor(0.5 * f);
      ob |= ((uint32_t)md) << (23 + sc);
    }
    // mbits: floor(mant * exp2emu(-s)) mod 2 -> word bits 22..0
#pragma unroll
    for (int sc = 22; sc >= 0; --sc) {
      double f = floor(mant * Lm[sc]);
      double md = f - 2.0 * floor(0.5 * f);
      ob |= ((uint32_t)md) << sc;
    }
  }

  // ---- emit 32 f32 pulses
  uint4* q = out + (size_t)v * 8;
#pragma unroll
  for (int j = 0; j < 8; ++j) {
    int base = 31 - 4 * j;
    uint4 o;
    o.x = ((ob >> base) & 1u) * 0x3F800000u;
    o.y = ((ob >> (base - 1)) & 1u) * 0x3F800000u;
    o.z = ((ob >> (base - 2)) & 1u) * 0x3F800000u;
    o.w = ((ob >> (base - 3)) & 1u) * 0x3F800000u;
    q[j] = o;
  }
}

extern "C" void kernel_launch(void* const* d_in, const int* in_sizes, int n_in,
                              void* d_out, int out_size, void* d_ws, size_t ws_size,
                              hipStream_t stream) {
  int n_vals = in_sizes[0] / 32;
  const int block = 256;
  int grid = (n_vals + block - 1) / block;
  spike_gelu_kernel<<<grid, block, 0, stream>>>(
      (const uint4*)d_in[0], (uint4*)d_out, n_vals);
}